// Round 5
// baseline (557.178 us; speedup 1.0000x reference)
//
#include <hip/hip_runtime.h>
#include <math.h>

#define N_NODES 50000
#define N_EDGES 800000
#define E_TOT   (N_EDGES + N_NODES)
#define HEADS   8
#define OUTC    10
#define HID     80
#define NEG_SLOPE 0.2f

// ---------------- CSR build ----------------

__global__ __launch_bounds__(256) void hist_k(const int* __restrict__ ei, int* __restrict__ cnt) {
    int e = blockIdx.x * blockDim.x + threadIdx.x;
    if (e >= E_TOT) return;
    int d = (e < N_EDGES) ? ei[N_EDGES + e] : (e - N_EDGES);
    atomicAdd(&cnt[d], 1);
}

__global__ __launch_bounds__(1024) void scan_k(const int* __restrict__ cnt, int* __restrict__ rowptr) {
    __shared__ int wsum[16];
    __shared__ int carry_s;
    const int tid = threadIdx.x;
    const int lane = tid & 63, wid = tid >> 6;
    if (tid == 0) carry_s = 0;
    __syncthreads();
    for (int base = 0; base < N_NODES; base += 1024) {
        int i = base + tid;
        int v = (i < N_NODES) ? cnt[i] : 0;
        int s = v;
        #pragma unroll
        for (int off = 1; off < 64; off <<= 1) {
            int t = __shfl_up(s, off, 64);
            if (lane >= off) s += t;
        }
        if (lane == 63) wsum[wid] = s;
        int carry = carry_s;
        __syncthreads();
        if (wid == 0 && lane < 16) {
            int w = wsum[lane];
            #pragma unroll
            for (int off = 1; off < 16; off <<= 1) {
                int t = __shfl_up(w, off, 16);
                if (lane >= off) w += t;
            }
            wsum[lane] = w;  // inclusive scan of wave sums
        }
        __syncthreads();
        int woff = (wid > 0) ? wsum[wid - 1] : 0;
        int incl = s + woff;
        int excl = incl - v;
        if (i < N_NODES) rowptr[i] = carry + excl;
        int total = wsum[15];
        __syncthreads();
        if (tid == 0) carry_s = carry + total;
        __syncthreads();
    }
    if (tid == 0) rowptr[N_NODES] = carry_s;
}

__global__ __launch_bounds__(256) void scatter_k(const int* __restrict__ ei,
                                                 const int* __restrict__ rowptr,
                                                 int* __restrict__ cursor,
                                                 int* __restrict__ csr) {
    int e = blockIdx.x * blockDim.x + threadIdx.x;
    if (e >= E_TOT) return;
    int s, d;
    if (e < N_EDGES) { s = ei[e]; d = ei[N_EDGES + e]; }
    else { s = e - N_EDGES; d = s; }
    int pos = rowptr[d] + atomicAdd(&cursor[d], 1);
    csr[pos] = s;
}

// ---------------- LDS-staged dual GEMM: xl = A@Wl, xr = A@Wr ----------------
// Block = 64 rows. A-tile (64x16) staged in LDS with 100%-line-utilization
// coalesced loads (thread t -> row t/4, 16B chunk t%4), then lane=row reads via
// ds_read_b128. W read wave-uniform (scalar pipe). Wave owns 40 of the 160
// virtual cols: waves 0,1 -> Wl cols 0-39/40-79; waves 2,3 -> Wr.

__global__ __launch_bounds__(256) void gemm3_k(const float* __restrict__ A, int K,
                                               const float* __restrict__ Wl,
                                               const float* __restrict__ Wr,
                                               float* __restrict__ xl,
                                               float* __restrict__ xr) {
    __shared__ float4 sa[64][4];   // 64 rows x 16 k
    const int tid = threadIdx.x;
    const int lane = tid & 63;
    const int wv = __builtin_amdgcn_readfirstlane(tid >> 6);
    const int mat = wv >> 1;                 // 0 -> Wl/xl, 1 -> Wr/xr
    const int j0 = (wv & 1) * 40;            // col base within the 80
    const int row0 = blockIdx.x * 64;
    const int row = row0 + lane;

    const float* __restrict__ W = mat ? Wr : Wl;
    float* __restrict__ Xo = mat ? xr : xl;

    // stage-load indices
    const int lr = tid >> 2;       // row 0..63
    const int lq = tid & 3;        // 16B chunk 0..3
    const int lrow = (row0 + lr < N_NODES) ? (row0 + lr) : (N_NODES - 1);
    const float* __restrict__ Asrc = A + (size_t)lrow * K + lq * 4;

    float acc[40];
    #pragma unroll
    for (int j = 0; j < 40; ++j) acc[j] = 0.f;

    for (int kb = 0; kb < K; kb += 16) {
        sa[lr][lq] = *reinterpret_cast<const float4*>(Asrc + kb);
        __syncthreads();

        float4 ar[4];
        #pragma unroll
        for (int q = 0; q < 4; ++q) ar[q] = sa[lane][q];

        #pragma unroll
        for (int q = 0; q < 4; ++q) {
            #pragma unroll
            for (int t = 0; t < 4; ++t) {
                const float av = (t == 0) ? ar[q].x : (t == 1) ? ar[q].y
                               : (t == 2) ? ar[q].z : ar[q].w;
                const float* __restrict__ wrow = W + (size_t)(kb + q * 4 + t) * HID + j0;
                #pragma unroll
                for (int c4 = 0; c4 < 10; ++c4) {
                    const float4 w = *reinterpret_cast<const float4*>(wrow + c4 * 4);
                    acc[c4 * 4 + 0] = fmaf(av, w.x, acc[c4 * 4 + 0]);
                    acc[c4 * 4 + 1] = fmaf(av, w.y, acc[c4 * 4 + 1]);
                    acc[c4 * 4 + 2] = fmaf(av, w.z, acc[c4 * 4 + 2]);
                    acc[c4 * 4 + 3] = fmaf(av, w.w, acc[c4 * 4 + 3]);
                }
            }
        }
        __syncthreads();
    }

    if (row < N_NODES) {
        float* op = Xo + (size_t)row * HID + j0;
        #pragma unroll
        for (int c4 = 0; c4 < 10; ++c4)
            *reinterpret_cast<float4*>(op + c4 * 4) =
                make_float4(acc[c4 * 4 + 0], acc[c4 * 4 + 1], acc[c4 * 4 + 2], acc[c4 * 4 + 3]);
    }
}

// ---------------- per-node online-softmax aggregation (lane = head) ----------
// one wave per node; lane&7 = head (10 channels, lane-local logit — no
// per-edge shuffles), lane>>3 = edge slot (8-way). 3 flash-merges at the end.

__global__ __launch_bounds__(256) void agg2_k(const float* __restrict__ xl,
                                              const float* __restrict__ xr,
                                              const int* __restrict__ rowptr,
                                              const int* __restrict__ csr,
                                              const float* __restrict__ att,
                                              const float* __restrict__ bias,
                                              float* __restrict__ out) {
    const int tid = threadIdx.x;
    const int lane = tid & 63;
    const int node = blockIdx.x * 4 + (tid >> 6);
    if (node >= N_NODES) return;
    const int eg = lane >> 3;   // edge slot 0..7
    const int h = lane & 7;     // head
    const int cb = h * 10;

    float att10[10], xr10[10];
    #pragma unroll
    for (int c = 0; c < 10; ++c) {
        att10[c] = att[cb + c];
        xr10[c] = xr[(size_t)node * HID + cb + c];
    }
    const int ro = rowptr[node];
    const int deg = rowptr[node + 1] - ro;

    float m = -INFINITY, s = 0.f;
    float acc[10];
    #pragma unroll
    for (int c = 0; c < 10; ++c) acc[c] = 0.f;

    for (int i = eg; i < deg; i += 8) {
        const int src = csr[ro + i];
        const float* xlp = xl + (size_t)src * HID + cb;
        float xl10[10];
        float logit = 0.f;
        #pragma unroll
        for (int c = 0; c < 10; ++c) {
            xl10[c] = xlp[c];
            float e = xl10[c] + xr10[c];
            e = (e > 0.f) ? e : NEG_SLOPE * e;
            logit = fmaf(e, att10[c], logit);
        }
        const float nm = fmaxf(m, logit);
        const float scale = __expf(m - nm);      // m=-inf -> 0
        const float p = __expf(logit - nm);
        s = s * scale + p;
        #pragma unroll
        for (int c = 0; c < 10; ++c) acc[c] = acc[c] * scale + p * xl10[c];
        m = nm;
    }

    // merge the 8 edge slots (flash state merge over lanes eg^1, eg^2, eg^4)
    #pragma unroll
    for (int off = 8; off <= 32; off <<= 1) {
        const float om = __shfl_xor(m, off, 64);
        const float os = __shfl_xor(s, off, 64);
        float oacc[10];
        #pragma unroll
        for (int c = 0; c < 10; ++c) oacc[c] = __shfl_xor(acc[c], off, 64);
        const float nm = fmaxf(m, om);
        const float sc1 = (m == -INFINITY) ? 0.f : __expf(m - nm);
        const float sc2 = (om == -INFINITY) ? 0.f : __expf(om - nm);
        s = s * sc1 + os * sc2;
        #pragma unroll
        for (int c = 0; c < 10; ++c) acc[c] = acc[c] * sc1 + oacc[c] * sc2;
        m = nm;
    }

    if (lane < 8) {
        const float inv = 1.f / (s + 1e-16f);
        #pragma unroll
        for (int c = 0; c < 10; ++c) {
            float v = acc[c] * inv + bias[cb + c];
            v = (v > 0.f) ? v : (__expf(v) - 1.f);   // ELU
            out[(size_t)node * HID + cb + c] = v;
        }
    }
}

// ---------------- launch ----------------

extern "C" void kernel_launch(void* const* d_in, const int* in_sizes, int n_in,
                              void* d_out, int out_size, void* d_ws, size_t ws_size,
                              hipStream_t stream) {
    const float* x  = (const float*)d_in[0];
    const int*   ei = (const int*)d_in[1];
    const float* Wl[3]   = {(const float*)d_in[2], (const float*)d_in[6],  (const float*)d_in[10]};
    const float* Wr[3]   = {(const float*)d_in[3], (const float*)d_in[7],  (const float*)d_in[11]};
    const float* attp[3] = {(const float*)d_in[4], (const float*)d_in[8],  (const float*)d_in[12]};
    const float* bp[3]   = {(const float*)d_in[5], (const float*)d_in[9],  (const float*)d_in[13]};

    char* ws = (char*)d_ws;
    size_t off = 0;
    auto alloc = [&](size_t bytes) -> void* {
        void* p = ws + off;
        off += (bytes + 255) & ~(size_t)255;
        return p;
    };
    int* cnt    = (int*)alloc((size_t)N_NODES * 4);
    int* cursor = (int*)alloc((size_t)N_NODES * 4);
    int* rowptr = (int*)alloc((size_t)(N_NODES + 1) * 4);
    int* csr    = (int*)alloc((size_t)E_TOT * 4);
    float* xl   = (float*)alloc((size_t)N_NODES * HID * 4);
    float* xr   = (float*)alloc((size_t)N_NODES * HID * 4);
    float* actA = (float*)alloc((size_t)N_NODES * HID * 4);
    float* actB = (float*)alloc((size_t)N_NODES * HID * 4);

    hipMemsetAsync(cnt, 0, (size_t)N_NODES * 4, stream);
    hipMemsetAsync(cursor, 0, (size_t)N_NODES * 4, stream);

    hist_k<<<(E_TOT + 255) / 256, 256, 0, stream>>>(ei, cnt);
    scan_k<<<1, 1024, 0, stream>>>(cnt, rowptr);
    scatter_k<<<(E_TOT + 255) / 256, 256, 0, stream>>>(ei, rowptr, cursor, csr);

    for (int l = 0; l < 3; ++l) {
        const float* act_in = (l == 0) ? x : (l == 1 ? actA : actB);
        const int K = (l == 0) ? 256 : 80;
        gemm3_k<<<(N_NODES + 63) / 64, 256, 0, stream>>>(act_in, K, Wl[l], Wr[l], xl, xr);
        float* out_l = (l == 0) ? actA : (l == 1 ? actB : (float*)d_out);
        agg2_k<<<N_NODES / 4, 256, 0, stream>>>(xl, xr, rowptr, csr, attp[l], bp[l], out_l);
    }
}